// Round 5
// baseline (428.111 us; speedup 1.0000x reference)
//
#include <hip/hip_runtime.h>
#include <hip/hip_bf16.h>
#include <stdint.h>

#define S_LEN 2048
#define E_DIM 128
#define QT 64
#define KT 32

typedef __attribute__((ext_vector_type(4))) float f32x4;
typedef __attribute__((ext_vector_type(4))) short s16x4;
typedef __attribute__((ext_vector_type(8))) short bf16x8;

__device__ __forceinline__ short f2bf(float f) {
    uint32_t u = __builtin_bit_cast(uint32_t, f);
    u += 0x7FFFu + ((u >> 16) & 1u);
    return (short)(u >> 16);
}
__device__ __forceinline__ float bf2f(short h) {
    uint32_t u = ((uint32_t)(uint16_t)h) << 16;
    return __builtin_bit_cast(float, u);
}

// Threefry-2x32, rotates via v_alignbit_b32 (rotl(x,n) = alignbit(x,x,32-n))
__device__ __forceinline__ void threefry_g(uint32_t k0, uint32_t k1,
                                           uint32_t c0, uint32_t c1,
                                           uint32_t& y0, uint32_t& y1) {
    uint32_t ks2 = k0 ^ k1 ^ 0x1BD11BDAu;
    uint32_t x0 = c0 + k0, x1 = c1 + k1;
#define TF_R(rr) { x0 += x1; x1 = __builtin_amdgcn_alignbit(x1, x1, 32u - rr); x1 ^= x0; }
    TF_R(13) TF_R(15) TF_R(26) TF_R(6)
    x0 += k1;  x1 += ks2 + 1u;
    TF_R(17) TF_R(29) TF_R(16) TF_R(24)
    x0 += ks2; x1 += k0 + 2u;
    TF_R(13) TF_R(15) TF_R(26) TF_R(6)
    x0 += k0;  x1 += k1 + 3u;
    TF_R(17) TF_R(29) TF_R(16) TF_R(24)
    x0 += k1;  x1 += ks2 + 4u;
    TF_R(13) TF_R(15) TF_R(26) TF_R(6)
    x0 += ks2; x1 += k0 + 5u;
#undef TF_R
    y0 = x0; y1 = x1;
}

// JAX partitionable threefry, x64 off: ctr=(0,j), draw = y0^y1, keep <=> draw < 0.9f form
__device__ __forceinline__ bool keep_bit(uint32_t j) {
    uint32_t y0, y1;
    threefry_g(0u, 42u, 0u, j, y0, y1);
    return (y0 ^ y1) < 0xE6666600u;
}

// P-tile swizzle: spreads rows {reg,4+reg,8+reg,12+reg} (g-lanes) across banks
__device__ __forceinline__ int pswz(int row) {
    return ((row ^ (row >> 2)) & 3) << 3;
}

__global__ __launch_bounds__(256, 4)
void attn_fwd(const float* __restrict__ Qg, const float* __restrict__ Kg,
              const float* __restrict__ Vg, float* __restrict__ Og) {
    __shared__ short kh[KT * E_DIM];      // 8 KB, swizzled ^((row&7)<<3)
    __shared__ short kl[KT * E_DIM];      // 8 KB
    __shared__ short vt[E_DIM * 34];      // 8.5 KB, V^T, row stride 34 elems
    __shared__ short pl[4][16 * KT];      // 4 KB, per-wave P tiles

    const int tid = threadIdx.x;
    const int w   = tid >> 6;
    const int ln  = tid & 63;
    const int r   = ln & 15;
    const int g   = ln >> 4;
    const int bid = blockIdx.x;
    const int b   = bid >> 5;
    const int q0  = (bid & 31) << 6;
    const size_t boff = (size_t)b * S_LEN * E_DIM;

    // ---------- self-tests (threefry-with-alignbit + MFMA layout) ----------
    bool kat1 = true, kat3 = true;
    int mfma_ok = 1;
    if (bid == 0 && w == 0) {
        uint32_t a0, a1;
        threefry_g(0u, 0u, 0u, 0u, a0, a1);
        kat1 = (a0 == 0x6b200159u && a1 == 0x99ba4efeu);
        threefry_g(0x13198a2eu, 0x03707344u, 0x243f6a88u, 0x85a308d3u, a0, a1);
        kat3 = (a0 == 0xc4923a9cu && a1 == 0x483df7a0u);
        bf16x8 af, bfr;
        #pragma unroll
        for (int i = 0; i < 8; ++i) {
            int k = g * 8 + i;
            af[i]  = f2bf((float)((r * 5 + k * 3) & 7));
            bfr[i] = f2bf((float)((k + r * 3) & 7));
        }
        f32x4 pc = {0.f, 0.f, 0.f, 0.f};
        pc = __builtin_amdgcn_mfma_f32_16x16x32_bf16(af, bfr, pc, 0, 0, 0);
        int ok = 1;
        #pragma unroll
        for (int j2 = 0; j2 < 4; ++j2) {
            int row = g * 4 + j2, col = r;
            float ex = 0.f;
            for (int k = 0; k < 32; ++k)
                ex += (float)((row * 5 + k * 3) & 7) * (float)((k + col * 3) & 7);
            if (pc[j2] != ex) ok = 0;
        }
        mfma_ok = __all(ok);
    }

    // ---- stage Q through the 32-row K buffers in two phases; preload frags --
    bf16x8 qh[4], ql[4];
    #pragma unroll
    for (int ph = 0; ph < 2; ++ph) {
        const float* src = Qg + boff + (size_t)(q0 + ph * 32) * E_DIM;
        const int e0 = (tid & 31) * 4;
        const int rb = tid >> 5;
        #pragma unroll
        for (int it = 0; it < 4; ++it) {
            int row = it * 8 + rb;
            f32x4 v = *(const f32x4*)(src + row * E_DIM + e0);
            s16x4 h, lo;
            #pragma unroll
            for (int i = 0; i < 4; ++i) {
                short hh = f2bf(v[i]);
                h[i]  = hh;
                lo[i] = f2bf(v[i] - bf2f(hh));
            }
            int idx = (row * E_DIM + e0) ^ ((row & 7) << 3);
            *(s16x4*)(kh + idx) = h;
            *(s16x4*)(kl + idx) = lo;
        }
        __syncthreads();
        if ((w >> 1) == ph) {
            int row = (w & 1) * 16 + r;
            #pragma unroll
            for (int ec = 0; ec < 4; ++ec) {
                int idx = (row * E_DIM + ec * 32 + g * 8) ^ ((row & 7) << 3);
                qh[ec] = *(const bf16x8*)(kh + idx);
                ql[ec] = *(const bf16x8*)(kl + idx);
            }
        }
        __syncthreads();
    }

    f32x4 oacc[8];
    #pragma unroll
    for (int i = 0; i < 8; ++i) oacc[i] = f32x4{0.f, 0.f, 0.f, 0.f};
    float mrun[4] = {-1e30f, -1e30f, -1e30f, -1e30f};
    float den[4]  = {0.f, 0.f, 0.f, 0.f};

    for (int kt = 0; kt < S_LEN / KT; ++kt) {
        // ---- stage K tile (split bf16, 32 rows) ----
        {
            const float* src = Kg + boff + (size_t)(kt * KT) * E_DIM;
            const int e0 = (tid & 31) * 4;
            const int rb = tid >> 5;
            #pragma unroll
            for (int it = 0; it < 4; ++it) {
                int row = it * 8 + rb;
                f32x4 v = *(const f32x4*)(src + row * E_DIM + e0);
                s16x4 h, lo;
                #pragma unroll
                for (int i = 0; i < 4; ++i) {
                    short hh = f2bf(v[i]);
                    h[i]  = hh;
                    lo[i] = f2bf(v[i] - bf2f(hh));
                }
                int idx = (row * E_DIM + e0) ^ ((row & 7) << 3);
                *(s16x4*)(kh + idx) = h;
                *(s16x4*)(kl + idx) = lo;
            }
        }
        // ---- stage V tile, transposed: vt[e][k], stride 34 ----
        {
            const float* src = Vg + boff + (size_t)(kt * KT) * E_DIM;
            const int e0 = (tid & 31) * 4;
            const int kb = (tid >> 5) * 2;
            #pragma unroll
            for (int it = 0; it < 2; ++it) {
                int k = it * 16 + kb;
                f32x4 a  = *(const f32x4*)(src + k * E_DIM + e0);
                f32x4 c2 = *(const f32x4*)(src + (k + 1) * E_DIM + e0);
                #pragma unroll
                for (int ci = 0; ci < 4; ++ci) {
                    uint32_t pack = (uint32_t)(uint16_t)f2bf(a[ci]) |
                                    ((uint32_t)(uint16_t)f2bf(c2[ci]) << 16);
                    *(uint32_t*)(vt + (e0 + ci) * 34 + k) = pack;
                }
            }
        }
        __syncthreads();

        // ---- S = Q K^T (16 rows x 32 cols per wave), 3-MFMA bf16 split ----
        f32x4 sc[2];
        #pragma unroll
        for (int c = 0; c < 2; ++c) {
            f32x4 acc = f32x4{0.f, 0.f, 0.f, 0.f};
            int krow = c * 16 + r;
            int sw = (krow & 7) << 3;
            #pragma unroll
            for (int ec = 0; ec < 4; ++ec) {
                int idx = (krow * E_DIM + ec * 32 + g * 8) ^ sw;
                bf16x8 bh = *(const bf16x8*)(kh + idx);
                bf16x8 bl = *(const bf16x8*)(kl + idx);
                acc = __builtin_amdgcn_mfma_f32_16x16x32_bf16(qh[ec], bh, acc, 0, 0, 0);
                acc = __builtin_amdgcn_mfma_f32_16x16x32_bf16(ql[ec], bh, acc, 0, 0, 0);
                acc = __builtin_amdgcn_mfma_f32_16x16x32_bf16(qh[ec], bl, acc, 0, 0, 0);
            }
            sc[c] = acc;
        }

        // ---- online softmax ----
        float scale[4];
        #pragma unroll
        for (int reg = 0; reg < 4; ++reg) {
            float v0 = fmaxf(sc[0][reg], sc[1][reg]);
            v0 = fmaxf(v0, __shfl_xor(v0, 1));
            v0 = fmaxf(v0, __shfl_xor(v0, 2));
            v0 = fmaxf(v0, __shfl_xor(v0, 4));
            v0 = fmaxf(v0, __shfl_xor(v0, 8));
            float mnew = fmaxf(mrun[reg], v0);
            scale[reg] = __expf(mrun[reg] - mnew);
            mrun[reg] = mnew;
        }
        float rs[4] = {0.f, 0.f, 0.f, 0.f};
        #pragma unroll
        for (int c = 0; c < 2; ++c) {
            #pragma unroll
            for (int reg = 0; reg < 4; ++reg) {
                float p = __expf(sc[c][reg] - mrun[reg]);
                sc[c][reg] = p;
                rs[reg] += p;
            }
        }
        #pragma unroll
        for (int reg = 0; reg < 4; ++reg) {
            float v0 = rs[reg];
            v0 += __shfl_xor(v0, 1);
            v0 += __shfl_xor(v0, 2);
            v0 += __shfl_xor(v0, 4);
            v0 += __shfl_xor(v0, 8);
            den[reg] = den[reg] * scale[reg] + v0;
        }
        #pragma unroll
        for (int et = 0; et < 8; ++et) {
            #pragma unroll
            for (int reg = 0; reg < 4; ++reg) oacc[et][reg] *= scale[reg];
        }

        // ---- dropout (partitionable threefry) + write P to LDS ----
        #pragma unroll
        for (int c = 0; c < 2; ++c) {
            int kcol = kt * KT + c * 16 + r;
            #pragma unroll
            for (int reg = 0; reg < 4; ++reg) {
                int row = g * 4 + reg;
                uint32_t q = (uint32_t)(q0 + w * 16 + row);
                uint32_t j = (((uint32_t)b << 11) + q) * 2048u + (uint32_t)kcol;
                float pm = keep_bit(j) ? sc[c][reg] * (1.0f / 0.9f) : 0.0f;
                int idx = (row * KT + (c * 16 + r)) ^ pswz(row);
                pl[w][idx] = f2bf(pm);
            }
        }

        // ---- O += P V (one MFMA per 16-e block; K=32 covers the tile) ----
        bf16x8 pa;
        {
            int idx = (r * KT + g * 8) ^ pswz(r);
            pa = *(const bf16x8*)(&pl[w][0] + idx);
        }
        #pragma unroll
        for (int et = 0; et < 8; ++et) {
            int e = et * 16 + r;
            union { bf16x8 v; uint32_t u[4]; } vb;
            #pragma unroll
            for (int i2 = 0; i2 < 4; ++i2)
                vb.u[i2] = *(const uint32_t*)(vt + e * 34 + g * 8 + i2 * 2);
            oacc[et] = __builtin_amdgcn_mfma_f32_16x16x32_bf16(pa, vb.v, oacc[et], 0, 0, 0);
        }
        __syncthreads();   // all waves done with kh/kl/vt before restage
    }

    // ---- epilogue ----
    float inv[4];
    #pragma unroll
    for (int reg = 0; reg < 4; ++reg) inv[reg] = 1.0f / den[reg];
    float* dst = Og + boff + (size_t)q0 * E_DIM;
    #pragma unroll
    for (int et = 0; et < 8; ++et) {
        #pragma unroll
        for (int reg = 0; reg < 4; ++reg) {
            int row = w * 16 + g * 4 + reg;
            int e = et * 16 + r;
            dst[row * E_DIM + e] = oacc[et][reg] * inv[reg];
        }
    }

    if (bid == 0 && tid == 0) {
        int plant = (kat1 ? 0 : 1000) + (kat3 ? 0 : 500) + (mfma_ok ? 0 : 250);
        if (plant) Og[0] = (float)plant;
    }
}

extern "C" void kernel_launch(void* const* d_in, const int* in_sizes, int n_in,
                              void* d_out, int out_size, void* d_ws, size_t ws_size,
                              hipStream_t stream) {
    (void)in_sizes; (void)n_in; (void)d_ws; (void)ws_size; (void)out_size;
    const float* Q = (const float*)d_in[0];
    const float* K = (const float*)d_in[1];
    const float* V = (const float*)d_in[2];
    float* O = (float*)d_out;
    hipLaunchKernelGGL(attn_fwd, dim3(16 * 32), dim3(256), 0, stream, Q, K, V, O);
}

// Round 6
// 419.618 us; speedup vs baseline: 1.0202x; 1.0202x over previous
//
#include <hip/hip_runtime.h>
#include <hip/hip_bf16.h>
#include <stdint.h>

#define S_LEN 2048
#define E_DIM 128
#define KT 32
#define KTM 64   // mono fallback tile

// ws layout: [0, 8 MiB): packed mask bits (uint32 words, bit j&31 of word j/32)
//            [8 MiB, ~42.5 MiB): split-K partials, 1024 blocks x 8320 floats
#define MASK_BYTES  (1u << 23)                 // 2^26 bits / 8
#define PART_FLOATS 8320                       // per block: m[64], den[64], O[64][128]
#define WS_NEEDED   (MASK_BYTES + (size_t)1024 * PART_FLOATS * 4)

typedef __attribute__((ext_vector_type(4))) float f32x4;
typedef __attribute__((ext_vector_type(4))) short s16x4;
typedef __attribute__((ext_vector_type(8))) short bf16x8;

__device__ __forceinline__ short f2bf(float f) {
    uint32_t u = __builtin_bit_cast(uint32_t, f);
    u += 0x7FFFu + ((u >> 16) & 1u);
    return (short)(u >> 16);
}
__device__ __forceinline__ float bf2f(short h) {
    uint32_t u = ((uint32_t)(uint16_t)h) << 16;
    return __builtin_bit_cast(float, u);
}

// Threefry-2x32, rotl via v_alignbit (KAT-certified on gfx950, r4/r5)
__device__ __forceinline__ void threefry_g(uint32_t k0, uint32_t k1,
                                           uint32_t c0, uint32_t c1,
                                           uint32_t& y0, uint32_t& y1) {
    uint32_t ks2 = k0 ^ k1 ^ 0x1BD11BDAu;
    uint32_t x0 = c0 + k0, x1 = c1 + k1;
#define TF_R(rr) { x0 += x1; x1 = __builtin_amdgcn_alignbit(x1, x1, 32u - rr); x1 ^= x0; }
    TF_R(13) TF_R(15) TF_R(26) TF_R(6)
    x0 += k1;  x1 += ks2 + 1u;
    TF_R(17) TF_R(29) TF_R(16) TF_R(24)
    x0 += ks2; x1 += k0 + 2u;
    TF_R(13) TF_R(15) TF_R(26) TF_R(6)
    x0 += k0;  x1 += k1 + 3u;
    TF_R(17) TF_R(29) TF_R(16) TF_R(24)
    x0 += k1;  x1 += ks2 + 4u;
    TF_R(13) TF_R(15) TF_R(26) TF_R(6)
    x0 += ks2; x1 += k0 + 5u;
#undef TF_R
    y0 = x0; y1 = x1;
}

// JAX partitionable threefry, x64 off: ctr=(0,j), draw=y0^y1, keep <=> draw<0.9f form
__device__ __forceinline__ bool keep_bit(uint32_t j) {
    uint32_t y0, y1;
    threefry_g(0u, 42u, 0u, j, y0, y1);
    return (y0 ^ y1) < 0xE6666600u;
}

__device__ __forceinline__ int pswz(int row) {
    return ((row ^ (row >> 2)) & 3) << 3;
}

// ============ kernel 1: mask pregen (pure VALU, ballot-packed) ============
__global__ __launch_bounds__(256, 8)
void maskgen(uint32_t* __restrict__ maskw) {
    const int lane = threadIdx.x & 63;
    const int wave = (blockIdx.x * 256 + threadIdx.x) >> 6;   // 0..8191
    uint64_t* out64 = (uint64_t*)maskw;
    for (uint32_t wi = wave; wi < (1u << 20); wi += 8192) {
        uint32_t j = wi * 64u + (uint32_t)lane;
        uint64_t m = __ballot(keep_bit(j));
        if (lane == 0) out64[wi] = m;
    }
}

// ============ kernel 2: split-K flash attention (partials to ws) ============
__global__ __launch_bounds__(256, 4)
void attn_split(const float* __restrict__ Qg, const float* __restrict__ Kg,
                const float* __restrict__ Vg, const uint32_t* __restrict__ maskw,
                float* __restrict__ part) {
    __shared__ short kh[KT * E_DIM];      // 8 KB, swizzled ^((row&7)<<3)
    __shared__ short kl[KT * E_DIM];      // 8 KB
    __shared__ short vt[E_DIM * 34];      // 8.5 KB V^T, stride 34 shorts
    __shared__ short pl[4][16 * KT];      // 4 KB per-wave P tiles

    const int tid = threadIdx.x;
    const int w   = tid >> 6;
    const int ln  = tid & 63;
    const int r   = ln & 15;
    const int g   = ln >> 4;
    const int bid = blockIdx.x;           // 1024 blocks
    const int t   = bid >> 1;             // output tile 0..511
    const int s   = bid & 1;              // K-split half
    const int b   = t >> 5;
    const int q0  = (t & 31) << 6;
    const int k0g = s * (S_LEN / 2);
    const size_t boff = (size_t)b * S_LEN * E_DIM;

    // ---- stage Q through K buffers in two 32-row phases; preload frags ----
    bf16x8 qh[4], ql[4];
    #pragma unroll
    for (int ph = 0; ph < 2; ++ph) {
        const float* src = Qg + boff + (size_t)(q0 + ph * 32) * E_DIM;
        const int e0 = (tid & 31) * 4;
        const int rb = tid >> 5;
        #pragma unroll
        for (int it = 0; it < 4; ++it) {
            int row = it * 8 + rb;
            f32x4 v = *(const f32x4*)(src + row * E_DIM + e0);
            s16x4 h, lo;
            #pragma unroll
            for (int i = 0; i < 4; ++i) {
                short hh = f2bf(v[i]);
                h[i]  = hh;
                lo[i] = f2bf(v[i] - bf2f(hh));
            }
            int idx = (row * E_DIM + e0) ^ ((row & 7) << 3);
            *(s16x4*)(kh + idx) = h;
            *(s16x4*)(kl + idx) = lo;
        }
        __syncthreads();
        if ((w >> 1) == ph) {
            int row = (w & 1) * 16 + r;
            #pragma unroll
            for (int ec = 0; ec < 4; ++ec) {
                int idx = (row * E_DIM + ec * 32 + g * 8) ^ ((row & 7) << 3);
                qh[ec] = *(const bf16x8*)(kh + idx);
                ql[ec] = *(const bf16x8*)(kl + idx);
            }
        }
        __syncthreads();
    }

    // per-reg mask word base: row q = q0 + w*16 + g*4 + reg; 64 words per row
    uint32_t mbase[4];
    #pragma unroll
    for (int reg = 0; reg < 4; ++reg) {
        uint32_t q = (uint32_t)(q0 + w * 16 + g * 4 + reg);
        mbase[reg] = (((uint32_t)b << 11) + q) * 64u + (uint32_t)(s * 32);
    }

    f32x4 oacc[8];
    #pragma unroll
    for (int i = 0; i < 8; ++i) oacc[i] = f32x4{0.f, 0.f, 0.f, 0.f};
    float mrun[4] = {-1e30f, -1e30f, -1e30f, -1e30f};
    float den[4]  = {0.f, 0.f, 0.f, 0.f};

    for (int kt = 0; kt < (S_LEN / 2) / KT; ++kt) {
        // mask words for this tile (issued early; broadcast within 16-lane grp)
        uint32_t mw[4];
        #pragma unroll
        for (int reg = 0; reg < 4; ++reg) mw[reg] = maskw[mbase[reg] + kt];

        // ---- stage K tile (split bf16, 32 rows) ----
        {
            const float* src = Kg + boff + (size_t)(k0g + kt * KT) * E_DIM;
            const int e0 = (tid & 31) * 4;
            const int rb = tid >> 5;
            #pragma unroll
            for (int it = 0; it < 4; ++it) {
                int row = it * 8 + rb;
                f32x4 v = *(const f32x4*)(src + row * E_DIM + e0);
                s16x4 h, lo;
                #pragma unroll
                for (int i = 0; i < 4; ++i) {
                    short hh = f2bf(v[i]);
                    h[i]  = hh;
                    lo[i] = f2bf(v[i] - bf2f(hh));
                }
                int idx = (row * E_DIM + e0) ^ ((row & 7) << 3);
                *(s16x4*)(kh + idx) = h;
                *(s16x4*)(kl + idx) = lo;
            }
        }
        // ---- stage V tile transposed: vt[e][k], stride 34 ----
        {
            const float* src = Vg + boff + (size_t)(k0g + kt * KT) * E_DIM;
            const int e0 = (tid & 31) * 4;
            const int kb = (tid >> 5) * 2;
            #pragma unroll
            for (int it = 0; it < 2; ++it) {
                int k = it * 16 + kb;
                f32x4 a  = *(const f32x4*)(src + k * E_DIM + e0);
                f32x4 c2 = *(const f32x4*)(src + (k + 1) * E_DIM + e0);
                #pragma unroll
                for (int ci = 0; ci < 4; ++ci) {
                    uint32_t pack = (uint32_t)(uint16_t)f2bf(a[ci]) |
                                    ((uint32_t)(uint16_t)f2bf(c2[ci]) << 16);
                    *(uint32_t*)(vt + (e0 + ci) * 34 + k) = pack;
                }
            }
        }
        __syncthreads();

        // ---- S = Q K^T (16x32 per wave), 3-MFMA bf16 split ----
        f32x4 sc[2];
        #pragma unroll
        for (int c = 0; c < 2; ++c) {
            f32x4 acc = f32x4{0.f, 0.f, 0.f, 0.f};
            int krow = c * 16 + r;
            int sw = (krow & 7) << 3;
            #pragma unroll
            for (int ec = 0; ec < 4; ++ec) {
                int idx = (krow * E_DIM + ec * 32 + g * 8) ^ sw;
                bf16x8 bh = *(const bf16x8*)(kh + idx);
                bf16x8 bl = *(const bf16x8*)(kl + idx);
                acc = __builtin_amdgcn_mfma_f32_16x16x32_bf16(qh[ec], bh, acc, 0, 0, 0);
                acc = __builtin_amdgcn_mfma_f32_16x16x32_bf16(ql[ec], bh, acc, 0, 0, 0);
                acc = __builtin_amdgcn_mfma_f32_16x16x32_bf16(qh[ec], bl, acc, 0, 0, 0);
            }
            sc[c] = acc;
        }

        // ---- online softmax ----
        float scale[4];
        #pragma unroll
        for (int reg = 0; reg < 4; ++reg) {
            float v0 = fmaxf(sc[0][reg], sc[1][reg]);
            v0 = fmaxf(v0, __shfl_xor(v0, 1));
            v0 = fmaxf(v0, __shfl_xor(v0, 2));
            v0 = fmaxf(v0, __shfl_xor(v0, 4));
            v0 = fmaxf(v0, __shfl_xor(v0, 8));
            float mnew = fmaxf(mrun[reg], v0);
            scale[reg] = __expf(mrun[reg] - mnew);
            mrun[reg] = mnew;
        }
        float rs[4] = {0.f, 0.f, 0.f, 0.f};
        #pragma unroll
        for (int c = 0; c < 2; ++c) {
            #pragma unroll
            for (int reg = 0; reg < 4; ++reg) {
                float p = __expf(sc[c][reg] - mrun[reg]);
                sc[c][reg] = p;
                rs[reg] += p;
            }
        }
        #pragma unroll
        for (int reg = 0; reg < 4; ++reg) {
            float v0 = rs[reg];
            v0 += __shfl_xor(v0, 1);
            v0 += __shfl_xor(v0, 2);
            v0 += __shfl_xor(v0, 4);
            v0 += __shfl_xor(v0, 8);
            den[reg] = den[reg] * scale[reg] + v0;
        }
        #pragma unroll
        for (int et = 0; et < 8; ++et) {
            #pragma unroll
            for (int reg = 0; reg < 4; ++reg) oacc[et][reg] *= scale[reg];
        }

        // ---- dropout via pregen mask bits + write P to LDS ----
        #pragma unroll
        for (int c = 0; c < 2; ++c) {
            #pragma unroll
            for (int reg = 0; reg < 4; ++reg) {
                int row = g * 4 + reg;
                bool keep = (mw[reg] >> (c * 16 + r)) & 1u;
                float pm = keep ? sc[c][reg] * (1.0f / 0.9f) : 0.0f;
                int idx = (row * KT + (c * 16 + r)) ^ pswz(row);
                pl[w][idx] = f2bf(pm);
            }
        }

        // ---- O += P V ----
        bf16x8 pa;
        {
            int idx = (r * KT + g * 8) ^ pswz(r);
            pa = *(const bf16x8*)(&pl[w][0] + idx);
        }
        #pragma unroll
        for (int et = 0; et < 8; ++et) {
            int e = et * 16 + r;
            union { bf16x8 v; uint32_t u[4]; } vb;
            #pragma unroll
            for (int i2 = 0; i2 < 4; ++i2)
                vb.u[i2] = *(const uint32_t*)(vt + e * 34 + g * 8 + i2 * 2);
            oacc[et] = __builtin_amdgcn_mfma_f32_16x16x32_bf16(pa, vb.v, oacc[et], 0, 0, 0);
        }
        __syncthreads();
    }

    // ---- store partials (unnormalized O, m, den) ----
    float* pb = part + (size_t)bid * PART_FLOATS;
    if (r == 0) {
        #pragma unroll
        for (int reg = 0; reg < 4; ++reg) {
            int row = w * 16 + g * 4 + reg;
            pb[row]      = mrun[reg];
            pb[64 + row] = den[reg];
        }
    }
    #pragma unroll
    for (int et = 0; et < 8; ++et) {
        #pragma unroll
        for (int reg = 0; reg < 4; ++reg) {
            int row = w * 16 + g * 4 + reg;
            int e = et * 16 + r;
            pb[128 + row * E_DIM + e] = oacc[et][reg];
        }
    }
}

// ============ kernel 3: merge split-K partials ============
__global__ __launch_bounds__(256, 8)
void merge_k(const float* __restrict__ part, float* __restrict__ Og) {
    const int t = blockIdx.x;             // 512 tiles
    const int b = t >> 5;
    const int q0 = (t & 31) << 6;
    const float* p0 = part + (size_t)(t * 2 + 0) * PART_FLOATS;
    const float* p1 = part + (size_t)(t * 2 + 1) * PART_FLOATS;
    float* dst = Og + (size_t)b * S_LEN * E_DIM + (size_t)q0 * E_DIM;
    for (int i = 0; i < 32; ++i) {
        int idx = i * 256 + threadIdx.x;
        int row = idx >> 7, e = idx & 127;
        float m0 = p0[row], m1 = p1[row];
        float mm = fmaxf(m0, m1);
        float s0 = __expf(m0 - mm), s1 = __expf(m1 - mm);
        float d = p0[64 + row] * s0 + p1[64 + row] * s1;
        float o = p0[128 + row * E_DIM + e] * s0 + p1[128 + row * E_DIM + e] * s1;
        dst[row * E_DIM + e] = o / d;
    }
}

// ============ fallback: round-4 mono kernel (certified 409 us) ============
__global__ __launch_bounds__(256, 2)
void attn_mono(const float* __restrict__ Qg, const float* __restrict__ Kg,
               const float* __restrict__ Vg, float* __restrict__ Og) {
    __shared__ short kh[KTM * E_DIM];
    __shared__ short kl[KTM * E_DIM];
    __shared__ short vt[E_DIM * 66];
    __shared__ short pl[4][16 * 64];

    const int tid = threadIdx.x;
    const int w   = tid >> 6;
    const int ln  = tid & 63;
    const int r   = ln & 15;
    const int g   = ln >> 4;
    const int bid = blockIdx.x;
    const int b   = bid >> 5;
    const int q0  = (bid & 31) << 6;
    const size_t boff = (size_t)b * S_LEN * E_DIM;

    {
        const float* src = Qg + boff + (size_t)q0 * E_DIM;
        const int e0 = (tid & 31) * 4;
        const int rb = tid >> 5;
        #pragma unroll
        for (int it = 0; it < 8; ++it) {
            int row = it * 8 + rb;
            f32x4 v = *(const f32x4*)(src + row * E_DIM + e0);
            s16x4 h, lo;
            #pragma unroll
            for (int i = 0; i < 4; ++i) {
                short hh = f2bf(v[i]);
                h[i]  = hh;
                lo[i] = f2bf(v[i] - bf2f(hh));
            }
            int idx = (row * E_DIM + e0) ^ ((row & 7) << 3);
            *(s16x4*)(kh + idx) = h;
            *(s16x4*)(kl + idx) = lo;
        }
    }
    __syncthreads();
    bf16x8 qh[4], ql[4];
    {
        int row = w * 16 + r;
        #pragma unroll
        for (int ec = 0; ec < 4; ++ec) {
            int idx = (row * E_DIM + ec * 32 + g * 8) ^ ((row & 7) << 3);
            qh[ec] = *(const bf16x8*)(kh + idx);
            ql[ec] = *(const bf16x8*)(kl + idx);
        }
    }
    f32x4 oacc[8];
    #pragma unroll
    for (int i = 0; i < 8; ++i) oacc[i] = f32x4{0.f, 0.f, 0.f, 0.f};
    float mrun[4] = {-1e30f, -1e30f, -1e30f, -1e30f};
    float den[4]  = {0.f, 0.f, 0.f, 0.f};

    for (int kt = 0; kt < S_LEN / KTM; ++kt) {
        __syncthreads();
        {
            const float* src = Kg + boff + (size_t)(kt * KTM) * E_DIM;
            const int e0 = (tid & 31) * 4;
            const int rb = tid >> 5;
            #pragma unroll
            for (int it = 0; it < 8; ++it) {
                int row = it * 8 + rb;
                f32x4 v = *(const f32x4*)(src + row * E_DIM + e0);
                s16x4 h, lo;
                #pragma unroll
                for (int i = 0; i < 4; ++i) {
                    short hh = f2bf(v[i]);
                    h[i]  = hh;
                    lo[i] = f2bf(v[i] - bf2f(hh));
                }
                int idx = (row * E_DIM + e0) ^ ((row & 7) << 3);
                *(s16x4*)(kh + idx) = h;
                *(s16x4*)(kl + idx) = lo;
            }
        }
        {
            const float* src = Vg + boff + (size_t)(kt * KTM) * E_DIM;
            const int e0 = (tid & 31) * 4;
            const int kb = (tid >> 5) * 2;
            #pragma unroll
            for (int it = 0; it < 4; ++it) {
                int k = it * 16 + kb;
                f32x4 a  = *(const f32x4*)(src + k * E_DIM + e0);
                f32x4 c2 = *(const f32x4*)(src + (k + 1) * E_DIM + e0);
                #pragma unroll
                for (int ci = 0; ci < 4; ++ci) {
                    uint32_t pack = (uint32_t)(uint16_t)f2bf(a[ci]) |
                                    ((uint32_t)(uint16_t)f2bf(c2[ci]) << 16);
                    *(uint32_t*)(vt + (e0 + ci) * 66 + k) = pack;
                }
            }
        }
        __syncthreads();
        f32x4 sc[4];
        #pragma unroll
        for (int c = 0; c < 4; ++c) {
            f32x4 acc = f32x4{0.f, 0.f, 0.f, 0.f};
            int krow = c * 16 + r;
            int sw = (krow & 7) << 3;
            #pragma unroll
            for (int ec = 0; ec < 4; ++ec) {
                int idx = (krow * E_DIM + ec * 32 + g * 8) ^ sw;
                bf16x8 bh = *(const bf16x8*)(kh + idx);
                bf16x8 bl = *(const bf16x8*)(kl + idx);
                acc = __builtin_amdgcn_mfma_f32_16x16x32_bf16(qh[ec], bh, acc, 0, 0, 0);
                acc = __builtin_amdgcn_mfma_f32_16x16x32_bf16(ql[ec], bh, acc, 0, 0, 0);
                acc = __builtin_amdgcn_mfma_f32_16x16x32_bf16(qh[ec], bl, acc, 0, 0, 0);
            }
            sc[c] = acc;
        }
        float scale[4];
        #pragma unroll
        for (int reg = 0; reg < 4; ++reg) {
            float v0 = fmaxf(fmaxf(sc[0][reg], sc[1][reg]),
                             fmaxf(sc[2][reg], sc[3][reg]));
            v0 = fmaxf(v0, __shfl_xor(v0, 1));
            v0 = fmaxf(v0, __shfl_xor(v0, 2));
            v0 = fmaxf(v0, __shfl_xor(v0, 4));
            v0 = fmaxf(v0, __shfl_xor(v0, 8));
            float mnew = fmaxf(mrun[reg], v0);
            scale[reg] = __expf(mrun[reg] - mnew);
            mrun[reg] = mnew;
        }
        float rs[4] = {0.f, 0.f, 0.f, 0.f};
        #pragma unroll
        for (int c = 0; c < 4; ++c) {
            #pragma unroll
            for (int reg = 0; reg < 4; ++reg) {
                float p = __expf(sc[c][reg] - mrun[reg]);
                sc[c][reg] = p;
                rs[reg] += p;
            }
        }
        #pragma unroll
        for (int reg = 0; reg < 4; ++reg) {
            float v0 = rs[reg];
            v0 += __shfl_xor(v0, 1);
            v0 += __shfl_xor(v0, 2);
            v0 += __shfl_xor(v0, 4);
            v0 += __shfl_xor(v0, 8);
            den[reg] = den[reg] * scale[reg] + v0;
        }
        #pragma unroll
        for (int et = 0; et < 8; ++et) {
            #pragma unroll
            for (int reg = 0; reg < 4; ++reg) oacc[et][reg] *= scale[reg];
        }
        #pragma unroll
        for (int c = 0; c < 4; ++c) {
            int kcol = kt * KTM + c * 16 + r;
            #pragma unroll
            for (int reg = 0; reg < 4; ++reg) {
                int row = g * 4 + reg;
                uint32_t q = (uint32_t)(q0 + w * 16 + row);
                uint32_t j = (((uint32_t)b << 11) + q) * 2048u + (uint32_t)kcol;
                float pm = keep_bit(j) ? sc[c][reg] * (1.0f / 0.9f) : 0.0f;
                int idx = (row * 64 + (c * 16 + r)) ^ ((row & 7) << 3);
                pl[w][idx] = f2bf(pm);
            }
        }
        bf16x8 pa[2];
        #pragma unroll
        for (int st = 0; st < 2; ++st) {
            int idx = (r * 64 + st * 32 + g * 8) ^ ((r & 7) << 3);
            pa[st] = *(const bf16x8*)(&pl[w][0] + idx);
        }
        #pragma unroll
        for (int et = 0; et < 8; ++et) {
            int e = et * 16 + r;
            f32x4 o = oacc[et];
            #pragma unroll
            for (int st = 0; st < 2; ++st) {
                union { bf16x8 v; uint32_t u[4]; } vb;
                #pragma unroll
                for (int i2 = 0; i2 < 4; ++i2)
                    vb.u[i2] = *(const uint32_t*)(vt + e * 66 + st * 32 + g * 8 + i2 * 2);
                o = __builtin_amdgcn_mfma_f32_16x16x32_bf16(pa[st], vb.v, o, 0, 0, 0);
            }
            oacc[et] = o;
        }
    }
    float inv[4];
    #pragma unroll
    for (int reg = 0; reg < 4; ++reg) inv[reg] = 1.0f / den[reg];
    float* dst = Og + boff + (size_t)q0 * E_DIM;
    #pragma unroll
    for (int et = 0; et < 8; ++et) {
        #pragma unroll
        for (int reg = 0; reg < 4; ++reg) {
            int row = w * 16 + g * 4 + reg;
            int e = et * 16 + r;
            dst[row * E_DIM + e] = oacc[et][reg] * inv[reg];
        }
    }
}

extern "C" void kernel_launch(void* const* d_in, const int* in_sizes, int n_in,
                              void* d_out, int out_size, void* d_ws, size_t ws_size,
                              hipStream_t stream) {
    (void)in_sizes; (void)n_in; (void)out_size;
    const float* Q = (const float*)d_in[0];
    const float* K = (const float*)d_in[1];
    const float* V = (const float*)d_in[2];
    float* O = (float*)d_out;
    if (ws_size >= WS_NEEDED) {
        uint32_t* maskw = (uint32_t*)d_ws;
        float* part = (float*)((char*)d_ws + MASK_BYTES);
        hipLaunchKernelGGL(maskgen, dim3(2048), dim3(256), 0, stream, maskw);
        hipLaunchKernelGGL(attn_split, dim3(1024), dim3(256), 0, stream,
                           Q, K, V, maskw, part);
        hipLaunchKernelGGL(merge_k, dim3(512), dim3(256), 0, stream, part, O);
    } else {
        hipLaunchKernelGGL(attn_mono, dim3(512), dim3(256), 0, stream, Q, K, V, O);
    }
}